// Round 1
// baseline (705.729 us; speedup 1.0000x reference)
//
#include <hip/hip_runtime.h>
#include <math.h>

#define N 8192
#define IN_F 512
#define OUTF 64
#define TI 16

typedef _Float16 f16x8 __attribute__((ext_vector_type(8)));
typedef float f32x4 __attribute__((ext_vector_type(4)));

// workspace layout (floats) — ~1.1 MB
#define OFF_HT   0u          // hT: 64x8192 f16 = 262144 float-slots
#define OFF_S    262144u     // 8192
#define OFF_T    270336u     // 8192
#define OFF_TMAX 278528u     // 16

__device__ __forceinline__ unsigned enc_f32(float f) {
  unsigned b = __float_as_uint(f);
  return b ^ ((unsigned)((int)b >> 31) | 0x80000000u);
}

// ---------------------------------------------------------------------------
// K1: hT[f][j] = (f16)(input@W)[j][f], s = h@a1, t = h@a2.  (unchanged)
// ---------------------------------------------------------------------------
__global__ __launch_bounds__(64) void k_precompute(
    const float* __restrict__ input, const float* __restrict__ W,
    const float* __restrict__ a, _Float16* __restrict__ hT,
    float* __restrict__ s, float* __restrict__ t) {
  const int lane = threadIdx.x;
  const int i0 = blockIdx.x * 4;

  float acc[4] = {0.f, 0.f, 0.f, 0.f};
  for (int c = 0; c < IN_F; c += 4) {
    const float w0 = W[(c + 0) * OUTF + lane];
    const float w1 = W[(c + 1) * OUTF + lane];
    const float w2 = W[(c + 2) * OUTF + lane];
    const float w3 = W[(c + 3) * OUTF + lane];
    #pragma unroll
    for (int r = 0; r < 4; r++) {
      const float4 iv = *(const float4*)(input + (size_t)(i0 + r) * IN_F + c);
      acc[r] += iv.x * w0 + iv.y * w1 + iv.z * w2 + iv.w * w3;
    }
  }

  union { _Float16 f[4]; uint2 u; } pk;
  #pragma unroll
  for (int r = 0; r < 4; r++) pk.f[r] = (_Float16)acc[r];
  *(uint2*)(hT + (size_t)lane * N + i0) = pk.u;

  const float a1v = a[lane];
  const float a2v = a[OUTF + lane];
  #pragma unroll
  for (int r = 0; r < 4; r++) {
    float sv = acc[r] * a1v;
    float tv = acc[r] * a2v;
    #pragma unroll
    for (int off = 1; off < 64; off <<= 1) {
      sv += __shfl_xor(sv, off);
      tv += __shfl_xor(tv, off);
    }
    if (lane == 0) {
      s[i0 + r] = sv;
      t[i0 + r] = tv;
    }
  }
}

// ---------------------------------------------------------------------------
// K1.5: tmax via atomicMax on monotone-encoded uint (memset-0 init). (unchanged)
// ---------------------------------------------------------------------------
__global__ __launch_bounds__(512) void k_tmax(const float* __restrict__ t,
                                              unsigned* __restrict__ tmax) {
  __shared__ float red[8];
  const int tid = threadIdx.x;
  float m = t[blockIdx.x * 512 + tid];
  #pragma unroll
  for (int off = 1; off < 64; off <<= 1) m = fmaxf(m, __shfl_xor(m, off));
  if ((tid & 63) == 0) red[tid >> 6] = m;
  __syncthreads();
  if (tid == 0) {
    #pragma unroll
    for (int w = 1; w < 8; w++) m = fmaxf(m, red[w]);
    atomicMax(tmax, enc_f32(m));
  }
}

// ---------------------------------------------------------------------------
// K2 v2: register-direct streaming attention.
//
// Every adj/adj_ad element feeds exactly ONE lane's MFMA A-fragment element —
// there is no cross-lane reuse, so LDS staging (and its producer/consumer
// barrier drain, which capped delivered BW at ~2.6 TB/s regardless of access
// pattern) is pure overhead. Each lane now global-loads its own 8-j slices
// directly, register-double-buffered one chunk ahead (named pa/pb, static
// indices). No barriers in the main loop; waves are independent streams with
// ~10-16 vector loads outstanding continuously. Per-WG column-start stagger
// (off) decorrelates the chip-wide footprint; legal since S and the MFMA
// accumulation are order-independent under the global bound Mr.
// 256 threads (4 waves), 16 rows/WG; LDS only for the epilogue reduce.
// ---------------------------------------------------------------------------
__global__ __launch_bounds__(256, 4) void k_attn(
    const _Float16* __restrict__ hT, const float* __restrict__ s,
    const float* __restrict__ t, const unsigned* __restrict__ tmaxp,
    const float* __restrict__ W_si, const float* __restrict__ W_ei,
    const float* __restrict__ adj_ad, const int* __restrict__ adj,
    float* __restrict__ out) {
  __shared__ float aLDS[4 * 1024];   // [wave][row16][f64]
  __shared__ float sLDS[4 * 64];     // [wave][lane]

  const int tid = threadIdx.x;
  const int wave = tid >> 6;
  const int lane = tid & 63;
  const int q = lane >> 4;
  const int m = lane & 15;
  const int i0 = blockIdx.x * TI;
  const int off = blockIdx.x & 15;   // column-phase stagger

  const float aei = fabsf(W_ei[0]);
  const float asi = fabsf(W_si[0]);
  const unsigned te = *tmaxp;
  const float tm = __uint_as_float((te & 0x80000000u) ? (te ^ 0x80000000u) : ~te);

  const float sr = s[i0 + m];
  const float xm = sr + tm;
  const float Mr = aei * fmaxf(xm, 0.2f * xm) + asi;  // row upper bound on e

  float S = 0.f;
  f32x4 acc[4];
  #pragma unroll
  for (int nb = 0; nb < 4; nb++) acc[nb] = (f32x4){0.f, 0.f, 0.f, 0.f};

  const size_t rowA = (size_t)(i0 + m) * N;

  // chunk c = 0..63; 32 j-columns per chunk; this lane covers cb..cb+7.
  // j-tile order per WG is rotated by `off` (order-independent math).
  auto CB = [&](int c) -> int {
    return ((((((c >> 2) + off) & 15) << 4) + (wave << 2) + (c & 3)) << 5) +
           (q << 3);
  };

  struct Pf { float4 a0, a1, t0, t1; int4 k0, k1; };

  auto LOADC = [&](int c) -> Pf {
    const int cb = CB(c);
    Pf p;
    p.a0 = *(const float4*)(adj_ad + rowA + cb);
    p.a1 = *(const float4*)(adj_ad + rowA + cb + 4);
    p.k0 = *(const int4*)(adj + rowA + cb);
    p.k1 = *(const int4*)(adj + rowA + cb + 4);
    p.t0 = *(const float4*)(t + cb);
    p.t1 = *(const float4*)(t + cb + 4);
    return p;
  };

  auto LHT = [&](int c, f16x8* fb) {
    const int cb = CB(c);
    #pragma unroll
    for (int nb = 0; nb < 4; nb++)
      fb[nb] = *(const f16x8*)(hT + (size_t)(nb * 16 + m) * N + cb);
  };

  auto COMPUTE = [&](const Pf& p, const f16x8* fb) {
    const float ad[8] = {p.a0.x, p.a0.y, p.a0.z, p.a0.w,
                         p.a1.x, p.a1.y, p.a1.z, p.a1.w};
    const int mk[8] = {p.k0.x, p.k0.y, p.k0.z, p.k0.w,
                       p.k1.x, p.k1.y, p.k1.z, p.k1.w};
    const float tv[8] = {p.t0.x, p.t0.y, p.t0.z, p.t0.w,
                         p.t1.x, p.t1.y, p.t1.z, p.t1.w};
    f16x8 fa;
    #pragma unroll
    for (int e = 0; e < 8; e++) {
      const float x = sr + tv[e];
      const float ee = aei * fmaxf(x, 0.2f * x) + asi * ad[e];
      const float pv = (mk[e] > 0) ? __expf(ee - Mr) : 0.f;
      S += pv;
      fa[e] = (_Float16)pv;
    }
    #pragma unroll
    for (int nb = 0; nb < 4; nb++)
      acc[nb] = __builtin_amdgcn_mfma_f32_16x16x32_f16(fa, fb[nb], acc[nb],
                                                       0, 0, 0);
  };

  // main loop: depth-2 register pipeline, no barriers, no LDS.
  Pf pa = LOADC(0);
  #pragma unroll 1
  for (int c = 0; c < 64; c += 2) {
    f16x8 fbA[4];
    LHT(c, fbA);                 // issue hT(c) early (L2-hot)
    Pf pb = LOADC(c + 1);        // prefetch next chunk
    COMPUTE(pa, fbA);            // consumes oldest loads; pb stays in flight
    f16x8 fbB[4];
    LHT(c + 1, fbB);
    pa = LOADC((c + 2) & 63);    // last iter reloads chunk 0 (negligible)
    COMPUTE(pb, fbB);
  }

  // ---- epilogue: cross-wave reduce in LDS ----
  sLDS[wave * 64 + lane] = S;
  #pragma unroll
  for (int nb = 0; nb < 4; nb++) {
    #pragma unroll
    for (int reg = 0; reg < 4; reg++) {
      aLDS[wave * 1024 + (q * 4 + reg) * 64 + nb * 16 + m] = acc[nb][reg];
    }
  }
  __syncthreads();

  #pragma unroll
  for (int ii = 0; ii < 4; ii++) {
    const int e = tid + 256 * ii;
    const int r = e >> 6;
    const int f = e & 63;
    float num = 0.f, den = 0.f;
    #pragma unroll
    for (int w = 0; w < 4; w++) {
      num += aLDS[w * 1024 + r * 64 + f];
      #pragma unroll
      for (int qq = 0; qq < 4; qq++) den += sLDS[w * 64 + qq * 16 + r];
    }
    const float x = num / den;
    out[(size_t)(i0 + r) * OUTF + f] = x > 0.f ? x : expm1f(x);
  }
}

// ---------------------------------------------------------------------------
extern "C" void kernel_launch(void* const* d_in, const int* in_sizes, int n_in,
                              void* d_out, int out_size, void* d_ws, size_t ws_size,
                              hipStream_t stream) {
  const float* input  = (const float*)d_in[0];
  const float* W      = (const float*)d_in[1];
  const float* a      = (const float*)d_in[2];
  const float* W_si   = (const float*)d_in[3];
  const float* W_ei   = (const float*)d_in[4];
  const float* adj_ad = (const float*)d_in[5];
  const int*   adj    = (const int*)d_in[6];
  float* out = (float*)d_out;
  float* ws  = (float*)d_ws;

  _Float16* hT   = (_Float16*)(ws + OFF_HT);
  float* s       = ws + OFF_S;
  float* t       = ws + OFF_T;
  unsigned* tmax = (unsigned*)(ws + OFF_TMAX);

  hipMemsetAsync(tmax, 0, 4, stream);
  k_precompute<<<N / 4, 64, 0, stream>>>(input, W, a, hT, s, t);
  k_tmax<<<N / 512, 512, 0, stream>>>(t, tmax);
  k_attn<<<N / TI, 256, 0, stream>>>(hT, s, t, tmax, W_si, W_ei,
                                     adj_ad, adj, out);
}

// Round 2
// 571.601 us; speedup vs baseline: 1.2347x; 1.2347x over previous
//
#include <hip/hip_runtime.h>
#include <math.h>

#define N 8192
#define IN_F 512
#define OUTF 64
#define TI 16
#define JT 256               // j-cols per tile
#define NTILE (N / JT)       // 32 phases
#define RS 260               // padded LDS row stride (floats)
#define NBUF 4               // buffer ring depth

typedef _Float16 f16x8 __attribute__((ext_vector_type(8)));
typedef float f32x4 __attribute__((ext_vector_type(4)));

typedef const void __attribute__((address_space(1)))* gptr_t;
typedef void __attribute__((address_space(3)))* lptr_t;

// workspace layout (floats) — ~1.1 MB
#define OFF_HT   0u          // hT: 64x8192 f16 = 262144 float-slots
#define OFF_S    262144u     // 8192
#define OFF_T    270336u     // 8192
#define OFF_TMAX 278528u     // 16

__device__ __forceinline__ unsigned enc_f32(float f) {
  unsigned b = __float_as_uint(f);
  return b ^ ((unsigned)((int)b >> 31) | 0x80000000u);
}

// ---------------------------------------------------------------------------
// K1: hT[f][j] = (f16)(input@W)[j][f], s = h@a1, t = h@a2.  (unchanged)
// ---------------------------------------------------------------------------
__global__ __launch_bounds__(64) void k_precompute(
    const float* __restrict__ input, const float* __restrict__ W,
    const float* __restrict__ a, _Float16* __restrict__ hT,
    float* __restrict__ s, float* __restrict__ t) {
  const int lane = threadIdx.x;
  const int i0 = blockIdx.x * 4;

  float acc[4] = {0.f, 0.f, 0.f, 0.f};
  for (int c = 0; c < IN_F; c += 4) {
    const float w0 = W[(c + 0) * OUTF + lane];
    const float w1 = W[(c + 1) * OUTF + lane];
    const float w2 = W[(c + 2) * OUTF + lane];
    const float w3 = W[(c + 3) * OUTF + lane];
    #pragma unroll
    for (int r = 0; r < 4; r++) {
      const float4 iv = *(const float4*)(input + (size_t)(i0 + r) * IN_F + c);
      acc[r] += iv.x * w0 + iv.y * w1 + iv.z * w2 + iv.w * w3;
    }
  }

  union { _Float16 f[4]; uint2 u; } pk;
  #pragma unroll
  for (int r = 0; r < 4; r++) pk.f[r] = (_Float16)acc[r];
  *(uint2*)(hT + (size_t)lane * N + i0) = pk.u;

  const float a1v = a[lane];
  const float a2v = a[OUTF + lane];
  #pragma unroll
  for (int r = 0; r < 4; r++) {
    float sv = acc[r] * a1v;
    float tv = acc[r] * a2v;
    #pragma unroll
    for (int off = 1; off < 64; off <<= 1) {
      sv += __shfl_xor(sv, off);
      tv += __shfl_xor(tv, off);
    }
    if (lane == 0) {
      s[i0 + r] = sv;
      t[i0 + r] = tv;
    }
  }
}

// ---------------------------------------------------------------------------
// K1.5: tmax via atomicMax on monotone-encoded uint (memset-0 init). (unchanged)
// ---------------------------------------------------------------------------
__global__ __launch_bounds__(512) void k_tmax(const float* __restrict__ t,
                                              unsigned* __restrict__ tmax) {
  __shared__ float red[8];
  const int tid = threadIdx.x;
  float m = t[blockIdx.x * 512 + tid];
  #pragma unroll
  for (int off = 1; off < 64; off <<= 1) m = fmaxf(m, __shfl_xor(m, off));
  if ((tid & 63) == 0) red[tid >> 6] = m;
  __syncthreads();
  if (tid == 0) {
    #pragma unroll
    for (int w = 1; w < 8; w++) m = fmaxf(m, red[w]);
    atomicMax(tmax, enc_f32(m));
  }
}

// ---------------------------------------------------------------------------
// K2 v3: counted-vmcnt staged pipeline (T3+T4 port).
//
// Round-0's producer/consumer + __syncthreads drained vmcnt(0) every phase
// (zero bytes in flight across each barrier) -> 2.6 TB/s duty-cycle cap.
// Round-1's register-direct scatter killed DRAM locality -> 1.15 TB/s.
// v3 keeps the row-contiguous 1KB global_load_lds staging but replaces the
// drain with a 4-deep buffer ring + hand `s_waitcnt vmcnt(14)` + raw
// s_barrier: tiles k+2/k+3 stay in flight ACROSS barriers (never vmcnt(0)).
// All 8 waves stage (4 x 1KB rows each) and compute (1 x 32-col chunk each).
// hT/t are reg-prefetched one phase ahead (compiler-protected loads; FIFO
// arithmetic keeps their waits from draining the stage queue).
// vmcnt(14) proof sketch: S(k+1) was issued 2 phases back; >=20 VMEM instrs
// (phase k-1: R 6 + S 4; phase k: R 6 + S 4) follow it in the FIFO, and
// barriers' "memory" clobbers stop cross-phase reordering -> leaving the
// newest 14 in flight always drains S(k+1). Prologue: after-S(0) >= 8 under
// any legal reorder (builtins keep order) -> vmcnt(8).
// ---------------------------------------------------------------------------
__global__ __launch_bounds__(512) void k_attn(
    const _Float16* __restrict__ hT, const float* __restrict__ s,
    const float* __restrict__ t, const unsigned* __restrict__ tmaxp,
    const float* __restrict__ W_si, const float* __restrict__ W_ei,
    const float* __restrict__ adj_ad, const int* __restrict__ adj,
    float* __restrict__ out) {
  __shared__ __align__(16) float bufA[NBUF][TI * RS];  // 66560 B
  __shared__ __align__(16) int   bufM[NBUF][TI * RS];  // 66560 B

  const int tid = threadIdx.x;
  const int w = tid >> 6;        // wave 0..7
  const int lane = tid & 63;
  const int q = lane >> 4;
  const int m = lane & 15;
  const int i0 = blockIdx.x * TI;

  const float aei = fabsf(W_ei[0]);
  const float asi = fabsf(W_si[0]);
  const unsigned te = *tmaxp;
  const float tm = __uint_as_float((te & 0x80000000u) ? (te ^ 0x80000000u) : ~te);

  const float sr = s[i0 + m];
  const float xm = sr + tm;
  const float Mr = aei * fmaxf(xm, 0.2f * xm) + asi;  // row upper bound on e

  float S = 0.f;
  f32x4 acc[4];
  #pragma unroll
  for (int nb = 0; nb < 4; nb++) acc[nb] = (f32x4){0.f, 0.f, 0.f, 0.f};

  const int r0 = w * 2;                       // this wave stages rows r0,r0+1
  const size_t gR0 = (size_t)(i0 + r0) * N;   // global row base
  const int cbl = w * 32 + q * 8;             // col-in-tile this lane computes
  const int lb = m * RS + cbl;                // LDS read offset (const/thread)

  // one instr = one row x 1KB contiguous; dest base wave-uniform, linear
  #define STAGE(kt)                                                           \
    {                                                                         \
      const int b_ = (kt) & (NBUF - 1);                                       \
      const int j0_ = (kt) * JT;                                              \
      __builtin_amdgcn_global_load_lds(                                       \
          (gptr_t)(adj_ad + gR0 + j0_ + lane * 4),                            \
          (lptr_t)&bufA[b_][r0 * RS], 16, 0, 0);                              \
      __builtin_amdgcn_global_load_lds(                                       \
          (gptr_t)(adj_ad + gR0 + N + j0_ + lane * 4),                        \
          (lptr_t)&bufA[b_][(r0 + 1) * RS], 16, 0, 0);                        \
      __builtin_amdgcn_global_load_lds(                                       \
          (gptr_t)(adj + gR0 + j0_ + lane * 4),                               \
          (lptr_t)&bufM[b_][r0 * RS], 16, 0, 0);                              \
      __builtin_amdgcn_global_load_lds(                                       \
          (gptr_t)(adj + gR0 + N + j0_ + lane * 4),                           \
          (lptr_t)&bufM[b_][(r0 + 1) * RS], 16, 0, 0);                        \
    }

  // reg-prefetch hT (4x f16x8) + t (2x float4) for tile kt — 6 VMEM instrs
  #define RLOAD(kt, H, T0, T1)                                                \
    {                                                                         \
      const int cb_ = (kt) * JT + cbl;                                        \
      _Pragma("unroll") for (int nb = 0; nb < 4; nb++)                        \
          H[nb] = *(const f16x8*)(hT + (size_t)(nb * 16 + m) * N + cb_);      \
      T0 = *(const float4*)(t + cb_);                                         \
      T1 = *(const float4*)(t + cb_ + 4);                                     \
    }

  #define COMPUTE(kt, H, T0, T1)                                              \
    {                                                                         \
      const int b_ = (kt) & (NBUF - 1);                                       \
      const float4 a0 = *(const float4*)&bufA[b_][lb];                        \
      const float4 a1 = *(const float4*)&bufA[b_][lb + 4];                    \
      const int4 k0 = *(const int4*)&bufM[b_][lb];                            \
      const int4 k1 = *(const int4*)&bufM[b_][lb + 4];                        \
      const float ad[8] = {a0.x, a0.y, a0.z, a0.w, a1.x, a1.y, a1.z, a1.w};   \
      const int mk[8] = {k0.x, k0.y, k0.z, k0.w, k1.x, k1.y, k1.z, k1.w};     \
      const float tv[8] = {T0.x, T0.y, T0.z, T0.w, T1.x, T1.y, T1.z, T1.w};   \
      f16x8 fa;                                                               \
      _Pragma("unroll") for (int e = 0; e < 8; e++) {                         \
        const float x = sr + tv[e];                                           \
        const float ee = aei * fmaxf(x, 0.2f * x) + asi * ad[e];              \
        const float pv = (mk[e] > 0) ? __expf(ee - Mr) : 0.f;                 \
        S += pv;                                                              \
        fa[e] = (_Float16)pv;                                                 \
      }                                                                       \
      _Pragma("unroll") for (int nb = 0; nb < 4; nb++)                        \
          acc[nb] = __builtin_amdgcn_mfma_f32_16x16x32_f16(fa, H[nb],         \
                                                           acc[nb], 0, 0, 0);\
    }

  #define PHASE_SYNC(n)                                                       \
    asm volatile("s_waitcnt vmcnt(" #n ")" ::: "memory");                     \
    __builtin_amdgcn_sched_barrier(0);                                        \
    __builtin_amdgcn_s_barrier();                                             \
    __builtin_amdgcn_sched_barrier(0);

  f16x8 hA[4], hB[4];
  float4 tA0, tA1, tB0, tB1;

  // prologue: S0, R0, S1, S2 -> need S0 resident: after-S0 >= 8 always
  STAGE(0);
  RLOAD(0, hA, tA0, tA1);
  STAGE(1);
  STAGE(2);
  PHASE_SYNC(8);

  #pragma unroll 1
  for (int k = 0; k < NTILE; k += 2) {
    // ---- phase k (even): compute tile k from hA; prefetch k+1 into hB ----
    RLOAD(k + 1, hB, tB0, tB1);
    if (k + 3 < NTILE) STAGE(k + 3);
    COMPUTE(k, hA, tA0, tA1);
    PHASE_SYNC(14);

    // ---- phase k+1 (odd): compute tile k+1 from hB; prefetch k+2 -> hA ----
    if (k + 2 < NTILE) RLOAD(k + 2, hA, tA0, tA1);
    if (k + 4 < NTILE) STAGE(k + 4);
    COMPUTE(k + 1, hB, tB0, tB1);
    PHASE_SYNC(14);
  }

  // ---- epilogue: cross-wave reduce in LDS ----
  // aLDS needs 8*1024 floats -> lives in bufA[0..1]; sLDS in bufM[0].
  // Last tiles used buffers 2,3 (30&3, 31&3) — regions disjoint, and the
  // final PHASE_SYNC barrier means every wave is past all buffer reads.
  float* aLDS = &bufA[0][0];
  float* sLDS = (float*)&bufM[0][0];

  sLDS[w * 64 + lane] = S;
  #pragma unroll
  for (int nb = 0; nb < 4; nb++) {
    #pragma unroll
    for (int reg = 0; reg < 4; reg++) {
      aLDS[w * 1024 + (q * 4 + reg) * 64 + nb * 16 + m] = acc[nb][reg];
    }
  }
  __syncthreads();

  #pragma unroll
  for (int ii = 0; ii < 2; ii++) {
    const int e = tid + 512 * ii;
    const int r = e >> 6;
    const int f = e & 63;
    float num = 0.f, den = 0.f;
    #pragma unroll
    for (int ww = 0; ww < 8; ww++) {
      num += aLDS[ww * 1024 + r * 64 + f];
      #pragma unroll
      for (int qq = 0; qq < 4; qq++) den += sLDS[ww * 64 + qq * 16 + r];
    }
    const float x = num / den;
    out[(size_t)(i0 + r) * OUTF + f] = x > 0.f ? x : expm1f(x);
  }
}

// ---------------------------------------------------------------------------
extern "C" void kernel_launch(void* const* d_in, const int* in_sizes, int n_in,
                              void* d_out, int out_size, void* d_ws, size_t ws_size,
                              hipStream_t stream) {
  const float* input  = (const float*)d_in[0];
  const float* W      = (const float*)d_in[1];
  const float* a      = (const float*)d_in[2];
  const float* W_si   = (const float*)d_in[3];
  const float* W_ei   = (const float*)d_in[4];
  const float* adj_ad = (const float*)d_in[5];
  const int*   adj    = (const int*)d_in[6];
  float* out = (float*)d_out;
  float* ws  = (float*)d_ws;

  _Float16* hT   = (_Float16*)(ws + OFF_HT);
  float* s       = ws + OFF_S;
  float* t       = ws + OFF_T;
  unsigned* tmax = (unsigned*)(ws + OFF_TMAX);

  hipMemsetAsync(tmax, 0, 4, stream);
  k_precompute<<<N / 4, 64, 0, stream>>>(input, W, a, hT, s, t);
  k_tmax<<<N / 512, 512, 0, stream>>>(t, tmax);
  k_attn<<<N / TI, 512, 0, stream>>>(hT, s, t, tmax, W_si, W_ei,
                                     adj_ad, adj, out);
}